// Round 12
// baseline (109.080 us; speedup 1.0000x reference)
//
#include <hip/hip_runtime.h>
#include <math.h>

// Problem constants
#define NT 64
#define NQ 1024
#define NK 1024
// ws layout in floats:
//   KWpack : [1024][32] float4 (vb.x,vb.y,vb.z, sb)      @ 0       (131072 floats)
//   QFpack : [32][1024] float4 (v.x, v.y, v.z, sa)       @ 131072  (131072 floats)
//   wvtab  : [32][8]    (w1L,w2L,w3L,w1A,w2A,w3A,0,0)    @ 262144  (256 floats)
//   KPpack : [1024] float4 (kx,ky,kz,0)                  @ 262400  (4096 floats)
#define WS_KW 0
#define WS_QF 131072
#define WS_WV 262144
#define WS_KP 262400

__launch_bounds__(256)
__global__ void prep_kernel(const float* __restrict__ qfeat,     // [1024][160]
                            const float* __restrict__ keyfeat,   // [1024][160]
                            const float* __restrict__ Wkey,      // [160][160]
                            const float* __restrict__ WvL,       // [96][32]
                            const float* __restrict__ WvA,       // [96][32]
                            const float* __restrict__ kcoord,    // [1024][3]
                            float* __restrict__ ws,
                            float* __restrict__ out) {
  const int blk = blockIdx.x;
  const int tid = threadIdx.x;
  if (blk < 128) {
    // KWpack: row r of key_feat @ W_key, columns (64+3c, 65+3c, 66+3c, c)
    // Only these 128 of 160 output columns are ever consumed downstream.
    const int g = blk * 256 + tid;          // 0..32767
    const int r = g >> 5;
    const int c = g & 31;
    const float* kf = keyfeat + r * 160;
    const int c0 = 64 + 3 * c;
    float a0 = 0.f, a1 = 0.f, a2 = 0.f, a3 = 0.f;
#pragma unroll 4
    for (int k = 0; k < 160; ++k) {
      const float f = kf[k];
      const float* wr = Wkey + k * 160;
      a0 = fmaf(f, wr[c0 + 0], a0);
      a1 = fmaf(f, wr[c0 + 1], a1);
      a2 = fmaf(f, wr[c0 + 2], a2);
      a3 = fmaf(f, wr[c], a3);
    }
    reinterpret_cast<float4*>(ws + WS_KW)[g] = make_float4(a0, a1, a2, a3);
  } else if (blk < 256) {
    // QFpack: (v[p][c], sa[p][c]) stored [c][p] so main-kernel reads coalesce
    const int g = (blk - 128) * 256 + tid;  // 0..32767
    const int p = g >> 5;
    const int c = g & 31;
    const float* q = qfeat + p * 160;
    float4 o = make_float4(q[64 + 3 * c], q[65 + 3 * c], q[66 + 3 * c], q[c]);
    reinterpret_cast<float4*>(ws + WS_QF)[c * 1024 + p] = o;
  } else {
    // (a) zero d_out (harness poisons it 0xAA; main_kernel accumulates atomically)
    out[tid] = 0.f;
    if (tid < 128) out[256 + tid] = 0.f;
    // (b) KPpack: float4 key table staged into LDS by the main kernel
    float4* kp = reinterpret_cast<float4*>(ws + WS_KP);
#pragma unroll
    for (int j = 0; j < 4; ++j) {
      const int k = j * 256 + tid;
      kp[k] = make_float4(kcoord[k * 3 + 0], kcoord[k * 3 + 1], kcoord[k * 3 + 2], 0.f);
    }
    // (c) wv means: .mean(axis=-2) over the 32 output channels commutes with
    // the einsum, so each 96->32 channel mix collapses to one 96-vector.
    if (tid < 32) {
      const int c = tid;
      float m0 = 0.f, m1 = 0.f, m2 = 0.f, m3 = 0.f, m4 = 0.f, m5 = 0.f;
      for (int o = 0; o < 32; ++o) {
        m0 += WvL[c * 32 + o];
        m1 += WvL[(32 + c) * 32 + o];
        m2 += WvL[(64 + c) * 32 + o];
        m3 += WvA[c * 32 + o];
        m4 += WvA[(32 + c) * 32 + o];
        m5 += WvA[(64 + c) * 32 + o];
      }
      float* wv = ws + WS_WV + c * 8;
      const float s = 1.0f / 32.0f;
      wv[0] = m0 * s; wv[1] = m1 * s; wv[2] = m2 * s;
      wv[3] = m3 * s; wv[4] = m4 * s; wv[5] = m5 * s;
      wv[6] = 0.f; wv[7] = 0.f;
    }
  }
}

// Q=4 / W=8: block = 8 waves x 512 threads covering 256 queries of one t.
// Wave w scans key-EIGHTH [128w,128w+128) via wave-uniform broadcast
// ds_read_b128, each thread serving FOUR queries -> DS-pipe work per CU is
// half of round-11's Q=2 (8 waves x 128 reads x 12cy ~ 5.1us), VALU ~8us/SIMD
// is now the floor. 256 blocks = 1 block/CU, 2 waves/SIMD.
__launch_bounds__(512)
__global__ void main_kernel(const float* __restrict__ T,        // [64][7]
                            const float* __restrict__ qweight,  // [1024]
                            const float* __restrict__ qcoord,   // [1024][3]
                            const float* __restrict__ ws,
                            float* __restrict__ out) {
  __shared__ float4 keys[1024];    // 16 KB staged keys
  __shared__ float2 cand[8][256];  // (d2, idx-bits) per wave per query
  __shared__ float red[8][8];
  const int tid  = threadIdx.x;
  const int lane = tid & 63;
  const int wu   = __builtin_amdgcn_readfirstlane(tid >> 6);  // wave id 0..7
  const int t    = blockIdx.x >> 2;          // 0..63
  const int pg   = blockIdx.x & 3;           // 256-query group within t

  // Stage keys (coalesced float4 reads from ws KPpack)
  {
    const float4* kp = reinterpret_cast<const float4*>(ws + WS_KP);
    keys[tid]       = kp[tid];
    keys[512 + tid] = kp[512 + tid];
  }

  // Load + normalize quaternion (uniform per block)
  const float* Tt = T + t * 7;
  float qw = Tt[0], qx = Tt[1], qy = Tt[2], qz = Tt[3];
  const float Xx = Tt[4], Xy = Tt[5], Xz = Tt[6];
  const float rn = rsqrtf(qw * qw + qx * qx + qy * qy + qz * qz);
  qw *= rn; qx *= rn; qy *= rn; qz *= rn;
  const float ix = -qx, iy = -qy, iz = -qz;  // conjugate (inverse rotation)

  // ---- Phase A: four queries per thread (q = pg*256 + j*64 + lane) ----
  // Lab-frame transformed query points: qc = quat_apply(q, qp) + X.
  // Subtract-first d2 mirrors the reference's rounding structure.
  float qcx[4], qcy[4], qcz[4];
#pragma unroll
  for (int j = 0; j < 4; ++j) {
    const int q = pg * 256 + j * 64 + lane;
    const float px = qcoord[q * 3 + 0];
    const float py = qcoord[q * 3 + 1];
    const float pz = qcoord[q * 3 + 2];
    const float ux = qy * pz - qz * py;
    const float uy = qz * px - qx * pz;
    const float uz = qx * py - qy * px;
    qcx[j] = px + 2.0f * (qw * ux + (qy * uz - qz * uy)) + Xx;
    qcy[j] = py + 2.0f * (qw * uy + (qz * ux - qx * uz)) + Xy;
    qcz[j] = pz + 2.0f * (qw * uz + (qx * uy - qy * ux)) + Xz;
  }

  __syncthreads();

  // Scan this wave's key-eighth in ASCENDING order; strict < keeps the
  // lowest index on ties (jnp.argmin first-min semantics).
  const int kbase = wu * 128;                // uniform
  float mv0 = 1e30f, mv1 = 1e30f, mv2 = 1e30f, mv3 = 1e30f;
  int mi0 = 0, mi1 = 0, mi2 = 0, mi3 = 0;
#pragma unroll 4
  for (int m = 0; m < 128; ++m) {
    const float4 K = keys[kbase + m];        // uniform addr -> broadcast read
    const float d0x = qcx[0] - K.x, d0y = qcy[0] - K.y, d0z = qcz[0] - K.z;
    const float d1x = qcx[1] - K.x, d1y = qcy[1] - K.y, d1z = qcz[1] - K.z;
    const float d2x = qcx[2] - K.x, d2y = qcy[2] - K.y, d2z = qcz[2] - K.z;
    const float d3x = qcx[3] - K.x, d3y = qcy[3] - K.y, d3z = qcz[3] - K.z;
    const float d0 = d0x * d0x + d0y * d0y + d0z * d0z;
    const float d1 = d1x * d1x + d1y * d1y + d1z * d1z;
    const float d2 = d2x * d2x + d2y * d2y + d2z * d2z;
    const float d3 = d3x * d3x + d3y * d3y + d3z * d3z;
    const int ki = kbase + m;
    if (d0 < mv0) { mv0 = d0; mi0 = ki; }
    if (d1 < mv1) { mv1 = d1; mi1 = ki; }
    if (d2 < mv2) { mv2 = d2; mi2 = ki; }
    if (d3 < mv3) { mv3 = d3; mi3 = ki; }
  }
  cand[wu][0 * 64 + lane] = make_float2(mv0, __int_as_float(mi0));
  cand[wu][1 * 64 + lane] = make_float2(mv1, __int_as_float(mi1));
  cand[wu][2 * 64 + lane] = make_float2(mv2, __int_as_float(mi2));
  cand[wu][3 * 64 + lane] = make_float2(mv3, __int_as_float(mi3));
  __syncthreads();

  // ---- Phase B: merge 8 wave-candidates, then feature math ----
  // 2 threads per query: pl = tid>>1 (0..255), sub = tid&1. Thread sub merges
  // waves {4sub..4sub+3} (ascending key ranges), then one shfl_xor(1)
  // completes the lexicographic (val, idx) argmin across all 8.
  const int pl  = tid >> 1;
  const int sub = tid & 1;
  float mv; int mi;
  {
    const float2 c0 = cand[4 * sub][pl];
    mv = c0.x; mi = __float_as_int(c0.y);
#pragma unroll
    for (int i = 1; i < 4; ++i) {
      const float2 ci = cand[4 * sub + i][pl];
      const float vi = ci.x; const int ii = __float_as_int(ci.y);
      if (vi < mv || (vi == mv && ii < mi)) { mv = vi; mi = ii; }
    }
    const float vo = __shfl_xor(mv, 1);
    const int   io = __shfl_xor(mi, 1);
    if (vo < mv || (vo == mv && io < mi)) { mv = vo; mi = io; }
  }
  const int minidx = mi;
  const float env = expf(-sqrtf(mv));

  const int pF = pg * 256 + pl;
  const float qpx = qcoord[pF * 3 + 0];
  const float qpy = qcoord[pF * 3 + 1];
  const float qpz = qcoord[pF * 3 + 2];

  // Feature math in the query-local frame, 16 channels per thread
  // (c = 2*jj + sub -> the 2 lanes of a pair read consecutive float4s):
  //   R^T[sa*vb + va'*sb + va' x vb] = sa*(R^T vb) + v*sb + v x (R^T vb)
  const float4* kwrow = reinterpret_cast<const float4*>(ws + WS_KW) + minidx * 32;
  const float4* qfp   = reinterpret_cast<const float4*>(ws + WS_QF) + pF;
  const float* wv = ws + WS_WV;
  float lx = 0.f, ly = 0.f, lz = 0.f, ax = 0.f, ay = 0.f, az = 0.f;
#pragma unroll
  for (int jj = 0; jj < 16; ++jj) {
    const int c = 2 * jj + sub;
    const float4 B = kwrow[c];          // (vb lab-frame, sb), pre-env
    const float4 A = qfp[c * 1024];     // (v local-frame, sa)
    // vb' = R^T vb
    const float uvx = iy * B.z - iz * B.y;
    const float uvy = iz * B.x - ix * B.z;
    const float uvz = ix * B.y - iy * B.x;
    const float bx = B.x + 2.0f * (qw * uvx + (iy * uvz - iz * uvy));
    const float by = B.y + 2.0f * (qw * uvy + (iz * uvx - ix * uvz));
    const float bz = B.z + 2.0f * (qw * uvz + (ix * uvy - iy * uvx));
    // cross(v, vb')
    const float crx = A.y * bz - A.z * by;
    const float cry = A.z * bx - A.x * bz;
    const float crz = A.x * by - A.y * bx;
    const float* w6 = wv + c * 8;
    const float a1L = w6[0] * A.w, a2L = w6[1] * B.w, w3L = w6[2];
    const float a1A = w6[3] * A.w, a2A = w6[4] * B.w, w3A = w6[5];
    lx = fmaf(a1L, bx, fmaf(a2L, A.x, fmaf(w3L, crx, lx)));
    ly = fmaf(a1L, by, fmaf(a2L, A.y, fmaf(w3L, cry, ly)));
    lz = fmaf(a1L, bz, fmaf(a2L, A.z, fmaf(w3L, crz, lz)));
    ax = fmaf(a1A, bx, fmaf(a2A, A.x, fmaf(w3A, crx, ax)));
    ay = fmaf(a1A, by, fmaf(a2A, A.y, fmaf(w3A, cry, ay)));
    az = fmaf(a1A, bz, fmaf(a2A, A.z, fmaf(w3A, crz, az)));
  }
  // one butterfly step sums the 2 channel-halves -> both lanes hold full sums
  lx += __shfl_xor(lx, 1); ly += __shfl_xor(ly, 1); lz += __shfl_xor(lz, 1);
  ax += __shfl_xor(ax, 1); ay += __shfl_xor(ay, 1); az += __shfl_xor(az, 1);
  // env scales kf linearly -> scales both dtp vector outputs linearly
  lx *= env; ly *= env; lz *= env;
  ax *= env; ay *= env; az *= env;

  // ang_orbital = qp x lin (local frame); weight by query_weight[pF].
  // Both lanes of a pair hold identical values; final sum scaled 0.5.
  const float wp = qweight[pF];
  const float ox = qpy * lz - qpz * ly;
  const float oy = qpz * lx - qpx * lz;
  const float oz = qpx * ly - qpy * lx;
  float r0 = wp * lx, r1 = wp * ly, r2 = wp * lz;
  float r3 = wp * (ox + ax), r4 = wp * (oy + ay), r5 = wp * (oz + az);

  // Wave reduce (64 lanes = 32 queries x 2 identical lanes), block reduce
  // across 8 waves, then device-scope atomicAdd (4 blocks/t contend: trivial).
#pragma unroll
  for (int m = 32; m >= 1; m >>= 1) {
    r0 += __shfl_xor(r0, m);
    r1 += __shfl_xor(r1, m);
    r2 += __shfl_xor(r2, m);
    r3 += __shfl_xor(r3, m);
    r4 += __shfl_xor(r4, m);
    r5 += __shfl_xor(r5, m);
  }
  if (lane == 0) {
    red[wu][0] = r0; red[wu][1] = r1; red[wu][2] = r2;
    red[wu][3] = r3; red[wu][4] = r4; red[wu][5] = r5;
  }
  __syncthreads();
  if (tid < 6) {
    float s = 0.f;
#pragma unroll
    for (int w = 0; w < 8; ++w) s += red[w][tid];
    const int row = (tid < 3) ? (t * 3 + tid) : (192 + t * 3 + (tid - 3));
    atomicAdd(out + row, s * 0.5f);   // 0.5: each query counted by 2 lanes
  }
}

extern "C" void kernel_launch(void* const* d_in, const int* in_sizes, int n_in,
                              void* d_out, int out_size, void* d_ws, size_t ws_size,
                              hipStream_t stream) {
  const float* T   = (const float*)d_in[0];   // [64][7]
  const float* qw  = (const float*)d_in[1];   // [1024]
  const float* qf  = (const float*)d_in[2];   // [1024][160]
  const float* qc  = (const float*)d_in[3];   // [1024][3]
  const float* kc  = (const float*)d_in[4];   // [1024][3]
  const float* kf  = (const float*)d_in[5];   // [1024][160]
  const float* Wk  = (const float*)d_in[6];   // [160][160]
  const float* WvL = (const float*)d_in[8];   // [96][32]  (Ws_* are dead outputs)
  const float* WvA = (const float*)d_in[10];  // [96][32]
  float* out = (float*)d_out;
  float* ws  = (float*)d_ws;

  prep_kernel<<<257, 256, 0, stream>>>(qf, kf, Wk, WvL, WvA, kc, ws, out);
  main_kernel<<<256, 512, 0, stream>>>(T, qw, qc, ws, out);
}

// Round 14
// 108.794 us; speedup vs baseline: 1.0026x; 1.0026x over previous
//
#include <hip/hip_runtime.h>
#include <math.h>

// Problem constants
#define NT 64
#define NQ 1024
#define NK 1024
// ws layout in floats:
//   KWpack : [1024][32] float4 (vb.x,vb.y,vb.z, sb)      @ 0       (131072 floats)
//   QFpack : [32][1024] float4 (v.x, v.y, v.z, sa)       @ 131072  (131072 floats)
//   wvtab  : [32][8]    (w1L,w2L,w3L,w1A,w2A,w3A,0,0)    @ 262144  (256 floats)
//   KPpack : [1024] float4 (kx,ky,kz,0)                  @ 262400  (4096 floats)
#define WS_KW 0
#define WS_QF 131072
#define WS_WV 262144
#define WS_KP 262400

__launch_bounds__(256)
__global__ void prep_kernel(const float* __restrict__ qfeat,     // [1024][160]
                            const float* __restrict__ keyfeat,   // [1024][160]
                            const float* __restrict__ Wkey,      // [160][160]
                            const float* __restrict__ WvL,       // [96][32]
                            const float* __restrict__ WvA,       // [96][32]
                            const float* __restrict__ kcoord,    // [1024][3]
                            float* __restrict__ ws,
                            float* __restrict__ out) {
  const int blk = blockIdx.x;
  const int tid = threadIdx.x;
  if (blk < 128) {
    // KWpack: row r of key_feat @ W_key, columns (64+3c, 65+3c, 66+3c, c)
    // Only these 128 of 160 output columns are ever consumed downstream.
    const int g = blk * 256 + tid;          // 0..32767
    const int r = g >> 5;
    const int c = g & 31;
    const float* kf = keyfeat + r * 160;
    const int c0 = 64 + 3 * c;
    float a0 = 0.f, a1 = 0.f, a2 = 0.f, a3 = 0.f;
#pragma unroll 4
    for (int k = 0; k < 160; ++k) {
      const float f = kf[k];
      const float* wr = Wkey + k * 160;
      a0 = fmaf(f, wr[c0 + 0], a0);
      a1 = fmaf(f, wr[c0 + 1], a1);
      a2 = fmaf(f, wr[c0 + 2], a2);
      a3 = fmaf(f, wr[c], a3);
    }
    reinterpret_cast<float4*>(ws + WS_KW)[g] = make_float4(a0, a1, a2, a3);
  } else if (blk < 256) {
    // QFpack: (v[p][c], sa[p][c]) stored [c][p] so main-kernel reads coalesce
    const int g = (blk - 128) * 256 + tid;  // 0..32767
    const int p = g >> 5;
    const int c = g & 31;
    const float* q = qfeat + p * 160;
    float4 o = make_float4(q[64 + 3 * c], q[65 + 3 * c], q[66 + 3 * c], q[c]);
    reinterpret_cast<float4*>(ws + WS_QF)[c * 1024 + p] = o;
  } else {
    // (a) zero d_out (harness poisons it 0xAA; main_kernel accumulates atomically)
    out[tid] = 0.f;
    if (tid < 128) out[256 + tid] = 0.f;
    // (b) KPpack: float4 key table staged into LDS by the main kernel
    float4* kp = reinterpret_cast<float4*>(ws + WS_KP);
#pragma unroll
    for (int j = 0; j < 4; ++j) {
      const int k = j * 256 + tid;
      kp[k] = make_float4(kcoord[k * 3 + 0], kcoord[k * 3 + 1], kcoord[k * 3 + 2], 0.f);
    }
    // (c) wv means: .mean(axis=-2) over the 32 output channels commutes with
    // the einsum, so each 96->32 channel mix collapses to one 96-vector.
    if (tid < 32) {
      const int c = tid;
      float m0 = 0.f, m1 = 0.f, m2 = 0.f, m3 = 0.f, m4 = 0.f, m5 = 0.f;
      for (int o = 0; o < 32; ++o) {
        m0 += WvL[c * 32 + o];
        m1 += WvL[(32 + c) * 32 + o];
        m2 += WvL[(64 + c) * 32 + o];
        m3 += WvA[c * 32 + o];
        m4 += WvA[(32 + c) * 32 + o];
        m5 += WvA[(64 + c) * 32 + o];
      }
      float* wv = ws + WS_WV + c * 8;
      const float s = 1.0f / 32.0f;
      wv[0] = m0 * s; wv[1] = m1 * s; wv[2] = m2 * s;
      wv[3] = m3 * s; wv[4] = m4 * s; wv[5] = m5 * s;
      wv[6] = 0.f; wv[7] = 0.f;
    }
  }
}

// Q=4 / S=16 / 4 waves/SIMD: 1024 blocks x 256 threads; block = 64 queries of
// one t (t = blk>>4). Thread (pl = tid>>4, sub = tid&15) serves pl's 4 queries,
// scanning keys k = 16m+sub -> each step the wave reads 16 CONSECUTIVE float4s
// (256B, all 32 banks, zero conflicts, no swizzle) broadcast to 4 pl-groups.
// 4 blocks/CU = 16 waves/CU = 4 waves/SIMD (2x R11/R12): the NN loop was
// latency-bound at 2 waves/SIMD (R12: halving DS work changed nothing).
__launch_bounds__(256)
__global__ void main_kernel(const float* __restrict__ T,        // [64][7]
                            const float* __restrict__ qweight,  // [1024]
                            const float* __restrict__ qcoord,   // [1024][3]
                            const float* __restrict__ ws,
                            float* __restrict__ out) {
  __shared__ float4 keys[1024];    // 16 KB staged keys
  __shared__ float2 cand[64];      // per-query (d2, idx-bits)
  __shared__ float red[4][8];
  const int tid  = threadIdx.x;
  const int lane = tid & 63;
  const int t    = blockIdx.x >> 4;          // 0..63
  const int qg   = blockIdx.x & 15;          // 64-query group within t
  const int sub  = tid & 15;                 // key-interleave id
  const int pl   = tid >> 4;                 // query-quad id 0..15

  // Stage keys (coalesced float4 reads from ws KPpack)
  {
    const float4* kp = reinterpret_cast<const float4*>(ws + WS_KP);
#pragma unroll
    for (int j = 0; j < 4; ++j) keys[j * 256 + tid] = kp[j * 256 + tid];
  }

  // Load + normalize quaternion (uniform per block)
  const float* Tt = T + t * 7;
  float qw = Tt[0], qx = Tt[1], qy = Tt[2], qz = Tt[3];
  const float Xx = Tt[4], Xy = Tt[5], Xz = Tt[6];
  const float rn = rsqrtf(qw * qw + qx * qx + qy * qy + qz * qz);
  qw *= rn; qx *= rn; qy *= rn; qz *= rn;
  const float ix = -qx, iy = -qy, iz = -qz;  // conjugate (inverse rotation)

  // ---- Phase A: each thread serves queries q = qg*64 + pl*4 + j ----
  // Lab-frame transformed query points: qc = quat_apply(q, qp) + X.
  // Subtract-first d2 mirrors the reference's rounding structure.
  float qcx[4], qcy[4], qcz[4];
#pragma unroll
  for (int j = 0; j < 4; ++j) {
    const int q = qg * 64 + pl * 4 + j;
    const float px = qcoord[q * 3 + 0];
    const float py = qcoord[q * 3 + 1];
    const float pz = qcoord[q * 3 + 2];
    const float ux = qy * pz - qz * py;
    const float uy = qz * px - qx * pz;
    const float uz = qx * py - qy * px;
    qcx[j] = px + 2.0f * (qw * ux + (qy * uz - qz * uy)) + Xx;
    qcy[j] = py + 2.0f * (qw * uy + (qz * ux - qx * uz)) + Xy;
    qcz[j] = pz + 2.0f * (qw * uz + (qx * uy - qy * ux)) + Xz;
  }

  __syncthreads();

  // Scan keys k = 16m + sub, m ascending; strict < keeps the lowest index
  // within the thread; butterfly below is lexicographic -> exact jnp.argmin.
  float mv0 = 1e30f, mv1 = 1e30f, mv2 = 1e30f, mv3 = 1e30f;
  int mi0 = 0, mi1 = 0, mi2 = 0, mi3 = 0;
#pragma unroll 8
  for (int m = 0; m < 64; ++m) {
    const float4 K = keys[16 * m + sub];  // 16 consecutive float4s per step
    const int ki = 16 * m + sub;
    const float d0x = qcx[0] - K.x, d0y = qcy[0] - K.y, d0z = qcz[0] - K.z;
    const float d1x = qcx[1] - K.x, d1y = qcy[1] - K.y, d1z = qcz[1] - K.z;
    const float d2x = qcx[2] - K.x, d2y = qcy[2] - K.y, d2z = qcz[2] - K.z;
    const float d3x = qcx[3] - K.x, d3y = qcy[3] - K.y, d3z = qcz[3] - K.z;
    const float d0 = d0x * d0x + d0y * d0y + d0z * d0z;
    const float d1 = d1x * d1x + d1y * d1y + d1z * d1z;
    const float d2 = d2x * d2x + d2y * d2y + d2z * d2z;
    const float d3 = d3x * d3x + d3y * d3y + d3z * d3z;
    if (d0 < mv0) { mv0 = d0; mi0 = ki; }
    if (d1 < mv1) { mv1 = d1; mi1 = ki; }
    if (d2 < mv2) { mv2 = d2; mi2 = ki; }
    if (d3 < mv3) { mv3 = d3; mi3 = ki; }
  }
  // 16-lane butterfly (masks 1,2,4,8) lexicographic argmin per query
#pragma unroll
  for (int msk = 1; msk <= 8; msk <<= 1) {
    float vo; int io;
    vo = __shfl_xor(mv0, msk); io = __shfl_xor(mi0, msk);
    if (vo < mv0 || (vo == mv0 && io < mi0)) { mv0 = vo; mi0 = io; }
    vo = __shfl_xor(mv1, msk); io = __shfl_xor(mi1, msk);
    if (vo < mv1 || (vo == mv1 && io < mi1)) { mv1 = vo; mi1 = io; }
    vo = __shfl_xor(mv2, msk); io = __shfl_xor(mi2, msk);
    if (vo < mv2 || (vo == mv2 && io < mi2)) { mv2 = vo; mi2 = io; }
    vo = __shfl_xor(mv3, msk); io = __shfl_xor(mi3, msk);
    if (vo < mv3 || (vo == mv3 && io < mi3)) { mv3 = vo; mi3 = io; }
  }
  if (sub == 0) {
    cand[pl * 4 + 0] = make_float2(mv0, __int_as_float(mi0));
    cand[pl * 4 + 1] = make_float2(mv1, __int_as_float(mi1));
    cand[pl * 4 + 2] = make_float2(mv2, __int_as_float(mi2));
    cand[pl * 4 + 3] = make_float2(mv3, __int_as_float(mi3));
  }
  __syncthreads();

  // ---- Phase B: feature math, 4 threads/query x 8 channels (R7 pattern) ----
  const int pq   = tid >> 2;                 // query-local 0..63
  const int sub2 = tid & 3;
  const float2 cc = cand[pq];                // broadcast read
  const int minidx = __float_as_int(cc.y);
  const float env = expf(-sqrtf(cc.x));

  const int pF = qg * 64 + pq;
  const float qpx = qcoord[pF * 3 + 0];
  const float qpy = qcoord[pF * 3 + 1];
  const float qpz = qcoord[pF * 3 + 2];

  //   R^T[sa*vb + va'*sb + va' x vb] = sa*(R^T vb) + v*sb + v x (R^T vb)
  const float4* kwrow = reinterpret_cast<const float4*>(ws + WS_KW) + minidx * 32;
  const float4* qfp   = reinterpret_cast<const float4*>(ws + WS_QF) + pF;
  const float* wv = ws + WS_WV;
  float lx = 0.f, ly = 0.f, lz = 0.f, ax = 0.f, ay = 0.f, az = 0.f;
#pragma unroll
  for (int jj = 0; jj < 8; ++jj) {
    const int c = 4 * jj + sub2;
    const float4 B = kwrow[c];          // (vb lab-frame, sb), pre-env
    const float4 A = qfp[c * 1024];     // (v local-frame, sa)
    // vb' = R^T vb
    const float uvx = iy * B.z - iz * B.y;
    const float uvy = iz * B.x - ix * B.z;
    const float uvz = ix * B.y - iy * B.x;
    const float bx = B.x + 2.0f * (qw * uvx + (iy * uvz - iz * uvy));
    const float by = B.y + 2.0f * (qw * uvy + (iz * uvx - ix * uvz));
    const float bz = B.z + 2.0f * (qw * uvz + (ix * uvy - iy * uvx));
    // cross(v, vb')
    const float crx = A.y * bz - A.z * by;
    const float cry = A.z * bx - A.x * bz;
    const float crz = A.x * by - A.y * bx;
    const float* w6 = wv + c * 8;
    const float a1L = w6[0] * A.w, a2L = w6[1] * B.w, w3L = w6[2];
    const float a1A = w6[3] * A.w, a2A = w6[4] * B.w, w3A = w6[5];
    lx = fmaf(a1L, bx, fmaf(a2L, A.x, fmaf(w3L, crx, lx)));
    ly = fmaf(a1L, by, fmaf(a2L, A.y, fmaf(w3L, cry, ly)));
    lz = fmaf(a1L, bz, fmaf(a2L, A.z, fmaf(w3L, crz, lz)));
    ax = fmaf(a1A, bx, fmaf(a2A, A.x, fmaf(w3A, crx, ax)));
    ay = fmaf(a1A, by, fmaf(a2A, A.y, fmaf(w3A, cry, ay)));
    az = fmaf(a1A, bz, fmaf(a2A, A.z, fmaf(w3A, crz, az)));
  }
  // 4-lane butterfly sum of channel partials -> all 4 lanes hold full sums
#pragma unroll
  for (int msk = 1; msk <= 2; msk <<= 1) {
    lx += __shfl_xor(lx, msk); ly += __shfl_xor(ly, msk); lz += __shfl_xor(lz, msk);
    ax += __shfl_xor(ax, msk); ay += __shfl_xor(ay, msk); az += __shfl_xor(az, msk);
  }
  // env scales kf linearly -> scales both dtp vector outputs linearly
  lx *= env; ly *= env; lz *= env;
  ax *= env; ay *= env; az *= env;

  // ang_orbital = qp x lin (local frame); weight by query_weight[pF].
  // All 4 lanes of a query compute identical values; final sum scaled 0.25.
  const float wp = qweight[pF];
  const float ox = qpy * lz - qpz * ly;
  const float oy = qpz * lx - qpx * lz;
  const float oz = qpx * ly - qpy * lx;
  float r0 = wp * lx, r1 = wp * ly, r2 = wp * lz;
  float r3 = wp * (ox + ax), r4 = wp * (oy + ay), r5 = wp * (oz + az);

  // Wave reduce (64 lanes = 16 queries x 4 identical lanes), block reduce
  // across 4 waves, then device-scope atomicAdd (16 blocks/t contend: trivial).
#pragma unroll
  for (int m = 32; m >= 1; m >>= 1) {
    r0 += __shfl_xor(r0, m);
    r1 += __shfl_xor(r1, m);
    r2 += __shfl_xor(r2, m);
    r3 += __shfl_xor(r3, m);
    r4 += __shfl_xor(r4, m);
    r5 += __shfl_xor(r5, m);
  }
  const int wave = tid >> 6;
  if (lane == 0) {
    red[wave][0] = r0; red[wave][1] = r1; red[wave][2] = r2;
    red[wave][3] = r3; red[wave][4] = r4; red[wave][5] = r5;
  }
  __syncthreads();
  if (tid < 6) {
    const float s = red[0][tid] + red[1][tid] + red[2][tid] + red[3][tid];
    const int row = (tid < 3) ? (t * 3 + tid) : (192 + t * 3 + (tid - 3));
    atomicAdd(out + row, s * 0.25f);   // 0.25: each query counted by 4 lanes
  }
}

extern "C" void kernel_launch(void* const* d_in, const int* in_sizes, int n_in,
                              void* d_out, int out_size, void* d_ws, size_t ws_size,
                              hipStream_t stream) {
  const float* T   = (const float*)d_in[0];   // [64][7]
  const float* qw  = (const float*)d_in[1];   // [1024]
  const float* qf  = (const float*)d_in[2];   // [1024][160]
  const float* qc  = (const float*)d_in[3];   // [1024][3]
  const float* kc  = (const float*)d_in[4];   // [1024][3]
  const float* kf  = (const float*)d_in[5];   // [1024][160]
  const float* Wk  = (const float*)d_in[6];   // [160][160]
  const float* WvL = (const float*)d_in[8];   // [96][32]  (Ws_* are dead outputs)
  const float* WvA = (const float*)d_in[10];  // [96][32]
  float* out = (float*)d_out;
  float* ws  = (float*)d_ws;

  prep_kernel<<<257, 256, 0, stream>>>(qf, kf, Wk, WvL, WvA, kc, ws, out);
  main_kernel<<<1024, 256, 0, stream>>>(T, qw, qc, ws, out);
}